// Round 2
// baseline (512.777 us; speedup 1.0000x reference)
//
#include <hip/hip_runtime.h>
#include <math.h>

// ---------------------------------------------------------------------------
// HierarchicalVAE, single persistent kernel for MI355X (gfx950), fp32.
// 256 blocks x 256 threads (1 block/CU guaranteed -> co-resident), stages
// separated by device-scope atomic grid barriers. Round-1 math preserved
// verbatim (absmax 3.9e-3), only the work distribution changed.
//
// Output layout (flat f32): rendered@0, mu@100352, logvar@108544,
// cp@116736, widths@124928, alphas@125184.
// ---------------------------------------------------------------------------

#define O_MU  100352
#define O_LV  108544
#define O_CP  116736
#define O_WD  124928
#define O_AL  125184

#define NBLK 256

// activation: 0=none 1=leaky_relu(0.2) 2=selu
template<int ACT>
__device__ __forceinline__ float act_fn(float x) {
    if (ACT == 1) return x >= 0.0f ? x : 0.2f * x;
    if (ACT == 2) {
        const float scale = 1.0507009873554805f;
        const float alpha = 1.6732632423543772f;
        return x > 0.0f ? scale * x : scale * (alpha * expm1f(x));
    }
    return x;
}

__device__ __forceinline__ void grid_barrier(unsigned* bar) {
    __syncthreads();
    if (threadIdx.x == 0) {
        __hip_atomic_fetch_add(bar, 1u, __ATOMIC_RELEASE, __HIP_MEMORY_SCOPE_AGENT);
        while (__hip_atomic_load(bar, __ATOMIC_ACQUIRE, __HIP_MEMORY_SCOPE_AGENT) < (unsigned)NBLK) {
            __builtin_amdgcn_s_sleep(2);
        }
    }
    __syncthreads();
}

// one 4-rows x 64-cols tile of C[128,N] = act(A[128,lda] @ W[K,N] + b)
template<int K, int N, int ACT>
__device__ void gemm_unit(const float* __restrict__ A, int lda,
                          const float* __restrict__ W, const float* __restrict__ bias,
                          float* __restrict__ outp, int r0, int j0,
                          float* __restrict__ sA, int tid) {
    for (int idx = tid; idx < 4 * K; idx += 256) {
        int r = idx / K;
        int k = idx - r * K;
        sA[r * K + k] = A[(r0 + r) * lda + k];
    }
    __syncthreads();
    const int r = tid >> 6;
    const int j = j0 + (tid & 63);
    float acc0 = bias[j], acc1 = 0.f, acc2 = 0.f, acc3 = 0.f;
    const float* __restrict__ a = sA + r * K;
    for (int k = 0; k < K; k += 4) {
        acc0 = fmaf(a[k + 0], W[(k + 0) * N + j], acc0);
        acc1 = fmaf(a[k + 1], W[(k + 1) * N + j], acc1);
        acc2 = fmaf(a[k + 2], W[(k + 2) * N + j], acc2);
        acc3 = fmaf(a[k + 3], W[(k + 3) * N + j], acc3);
    }
    float acc = (acc0 + acc1) + (acc2 + acc3);
    outp[(r0 + r) * N + j] = act_fn<ACT>(acc);
}

// mu, logvar, z for 2 rows (r0, r0+1)
__device__ void muvz_unit(int r0, const float* __restrict__ h,
                          const float* __restrict__ mu_w, const float* __restrict__ mu_b,
                          const float* __restrict__ lv_w, const float* __restrict__ lv_b,
                          const float* __restrict__ eps,
                          float* __restrict__ out, float* __restrict__ hin,
                          float* __restrict__ smem, int tid) {
    float* sA = smem;        // 2*256
    float* sO = smem + 512;  // 2*128
    for (int idx = tid; idx < 512; idx += 256)
        sA[idx] = h[(r0 + (idx >> 8)) * 256 + (idx & 255)];
    __syncthreads();
    {
        const int r = tid >> 7;
        const int o = tid & 127;
        const int j = o & 63;
        const bool is_lv = o >= 64;
        const float* __restrict__ W = is_lv ? lv_w : mu_w;
        float acc = is_lv ? lv_b[j] : mu_b[j];
        const float* __restrict__ a = sA + r * 256;
        for (int k = 0; k < 256; k += 4) {
            acc = fmaf(a[k + 0], W[(k + 0) * 64 + j], acc);
            acc = fmaf(a[k + 1], W[(k + 1) * 64 + j], acc);
            acc = fmaf(a[k + 2], W[(k + 2) * 64 + j], acc);
            acc = fmaf(a[k + 3], W[(k + 3) * 64 + j], acc);
        }
        sO[r * 128 + o] = acc;
        out[(is_lv ? O_LV : O_MU) + (r0 + r) * 64 + j] = acc;
    }
    __syncthreads();
    if (tid < 128) {
        const int r = tid >> 6;
        const int j = tid & 63;
        float mu = sO[r * 128 + j];
        float lv = sO[r * 128 + 64 + j];
        hin[(r0 + r) * 92 + j] = fmaf(eps[(r0 + r) * 64 + j], expf(0.5f * lv), mu);
    }
}

// cp head (-> pts_norm into hin[64:92]), widths, alphas for one row
__device__ void heads_unit(int row, const float* __restrict__ h2,
                           const float* __restrict__ cp_w, const float* __restrict__ cp_b,
                           const float* __restrict__ wd_w, const float* __restrict__ wd_b,
                           const float* __restrict__ al_w, const float* __restrict__ al_b,
                           float* __restrict__ out, float* __restrict__ hin,
                           float* __restrict__ smem, int tid) {
    float* sH = smem;  // 512
    for (int i = tid; i < 512; i += 256) sH[i] = h2[row * 512 + i];
    __syncthreads();
    const int o = tid >> 3;
    const int g = tid & 7;
    const float* __restrict__ W;
    int ldw, col;
    if (o < 28)      { W = cp_w; ldw = 28; col = o; }
    else if (o < 30) { W = wd_w; ldw = 2;  col = o - 28; }
    else             { W = al_w; ldw = 2;  col = o - 30; }
    float acc = 0.f;
    for (int k = g; k < 512; k += 8) acc = fmaf(sH[k], W[k * ldw + col], acc);
    acc += __shfl_xor(acc, 1);
    acc += __shfl_xor(acc, 2);
    acc += __shfl_xor(acc, 4);
    if (g == 0) {
        if (o < 28) {
            hin[row * 92 + 64 + o] = tanhf(acc + cp_b[col]);
        } else if (o < 30) {
            float v = 1.f / (1.f + expf(-(acc + wd_b[col])));
            out[O_WD + row * 2 + col] = fmaf(v, 2.f, 1.f);
        } else {
            float v = 1.f / (1.f + expf(-(acc + al_b[col])));
            out[O_AL + row * 2 + col] = v;
        }
    }
}

// refined -> points -> control_points (out) + polyline q (ws), one row
__device__ void final_unit(int row, const float* __restrict__ r1,
                           const float* __restrict__ w2, const float* __restrict__ b2,
                           float* __restrict__ out, float* __restrict__ q,
                           float* __restrict__ smem, int tid) {
    float* sR = smem;        // 512
    float* sP = smem + 512;  // 52
    for (int i = tid; i < 512; i += 256) sR[i] = r1[row * 512 + i];
    __syncthreads();
    const int o = tid >> 2;
    const int g = tid & 3;
    float acc = 0.f;
    if (o < 52)
        for (int k = g; k < 512; k += 4) acc = fmaf(sR[k], w2[k * 52 + o], acc);
    acc += __shfl_xor(acc, 1);
    acc += __shfl_xor(acc, 2);
    if (g == 0 && o < 52)
        sP[o] = fmaf(tanhf(acc + b2[o]), 12.f, 14.f);  // *SCALE + HALF
    __syncthreads();
    if (tid < 64) {
        int idx = tid;
        int p = idx >> 5, rest = idx & 31;
        int s = rest >> 3, kk = (rest >> 1) & 3, d = idx & 1;
        out[O_CP + row * 64 + idx] = sP[p * 26 + (3 * s + kk) * 2 + d];
    }
    if (tid < 128) {
        int idx = tid;
        int p = idx >> 6, s = (idx >> 4) & 3, ti = (idx >> 1) & 7, d = idx & 1;
        float t = (float)ti / 7.0f;
        float mt = 1.0f - t;
        float c0 = mt * mt * mt;
        float c1 = 3.f * mt * mt * t;
        float c2 = 3.f * mt * t * t;
        float c3 = t * t * t;
        const float* base = sP + p * 26 + (3 * s) * 2 + d;
        q[row * 128 + idx] = c0 * base[0] + c1 * base[2] + c2 * base[4] + c3 * base[6];
    }
}

// one (row, 64-pixel chunk) raster unit; thread = pixel*4 + AA subsample
__device__ void raster_unit(int u, const float* __restrict__ qb,
                            float* __restrict__ out, float* __restrict__ smem, int tid) {
    const int row = u / 13;
    const int chunk = u - row * 13;
    float* sWA = smem + 128;
    __syncthreads();  // protect LDS reuse across loop iterations
    if (tid < 128) smem[tid] = qb[row * 128 + tid];
    if (tid < 4) sWA[tid] = (tid < 2) ? out[O_WD + row * 2 + tid]
                                      : out[O_AL + row * 2 + (tid - 2)];
    __syncthreads();
    const int pixel = chunk * 64 + (tid >> 2);
    const int sub = tid & 3;
    if (pixel < 784) {
        const int py = pixel / 28;
        const int px = pixel - py * 28;
        const float sy = ((float)(2 * py + (sub >> 1)) + 0.5f) * 0.5f;
        const float sx = ((float)(2 * px + (sub & 1)) + 0.5f) * 0.5f;
        const float2* sQ = (const float2*)smem;
        float img = 1.0f;
#pragma unroll
        for (int p = 0; p < 2; p++) {
            float dmin2 = 1e30f;
            int cnt = 0;
            float2 cur = sQ[p * 32];
            bool bp = cur.y > sy;
#pragma unroll
            for (int m = 0; m < 32; m++) {
                float2 nxt = sQ[p * 32 + ((m + 1) & 31)];
                float dx = sx - cur.x;
                float dy = sy - cur.y;
                dmin2 = fminf(dmin2, fmaf(dx, dx, dy * dy));
                bool bn = nxt.y > sy;
                float den = nxt.y - cur.y + 1e-8f;
                float lhs = (sx - cur.x) * den;
                float rhs = (sy - cur.y) * (nxt.x - cur.x);
                if ((bp != bn) && ((lhs < rhs) == (den > 0.0f))) cnt++;
                cur = nxt;
                bp = bn;
            }
            float dist = sqrtf(dmin2);
            float stroke = fminf(fmaxf(fmaf(sWA[p], 0.5f, 0.5f) - dist, 0.f), 1.f);
            float cov = fmaxf((float)(cnt & 1), stroke);
            img *= fmaf(-sWA[2 + p], cov, 1.0f);
        }
        img += __shfl_xor(img, 1);
        img += __shfl_xor(img, 2);
        if (sub == 0) out[row * 784 + pixel] = 1.0f - 0.25f * img;
    }
}

__global__ __launch_bounds__(256, 1)
void mega(const float* __restrict__ x, const float* __restrict__ eps,
          const float* __restrict__ enc_w1, const float* __restrict__ enc_b1,
          const float* __restrict__ enc_w2, const float* __restrict__ enc_b2,
          const float* __restrict__ mu_w, const float* __restrict__ mu_b,
          const float* __restrict__ lv_w, const float* __restrict__ lv_b,
          const float* __restrict__ dec_w1, const float* __restrict__ dec_b1,
          const float* __restrict__ dec_w2, const float* __restrict__ dec_b2,
          const float* __restrict__ cp_w, const float* __restrict__ cp_b,
          const float* __restrict__ ref_w1, const float* __restrict__ ref_b1,
          const float* __restrict__ ref_w2, const float* __restrict__ ref_b2,
          const float* __restrict__ wd_w, const float* __restrict__ wd_b,
          const float* __restrict__ al_w, const float* __restrict__ al_b,
          float* __restrict__ out, unsigned* __restrict__ bars,
          float* __restrict__ h1, float* __restrict__ h, float* __restrict__ hin,
          float* __restrict__ d1, float* __restrict__ h2, float* __restrict__ r1,
          float* __restrict__ qb) {
    __shared__ float smem[3136];  // max stage need: 4*784 floats (enc1)
    const int bid = blockIdx.x;
    const int tid = threadIdx.x;

    // enc1: 784->256 leaky. 128 units of 4 rows x 64 cols.
    if (bid < 128)
        gemm_unit<784, 256, 1>(x, 784, enc_w1, enc_b1, h1, (bid >> 2) * 4, (bid & 3) * 64, smem, tid);
    grid_barrier(bars + 0);

    // enc2: 256->256 leaky.
    if (bid < 128)
        gemm_unit<256, 256, 1>(h1, 256, enc_w2, enc_b2, h, (bid >> 2) * 4, (bid & 3) * 64, smem, tid);
    grid_barrier(bars + 1);

    // mu / logvar / z (z into hin[:,0:64])
    if (bid < 64)
        muvz_unit(bid * 2, h, mu_w, mu_b, lv_w, lv_b, eps, out, hin, smem, tid);
    grid_barrier(bars + 2);

    // dec1: 64->512 selu (reads z cols of hin). 256 units.
    gemm_unit<64, 512, 2>(hin, 92, dec_w1, dec_b1, d1, (bid >> 3) * 4, (bid & 7) * 64, smem, tid);
    grid_barrier(bars + 3);

    // dec2: 512->512 selu. 256 units.
    gemm_unit<512, 512, 2>(d1, 512, dec_w2, dec_b2, h2, (bid >> 3) * 4, (bid & 7) * 64, smem, tid);
    grid_barrier(bars + 4);

    // heads: cp (pts_norm -> hin[:,64:92]), widths, alphas. 128 rows.
    if (bid < 128)
        heads_unit(bid, h2, cp_w, cp_b, wd_w, wd_b, al_w, al_b, out, hin, smem, tid);
    grid_barrier(bars + 5);

    // ref1: 92->512 selu. 256 units.
    gemm_unit<92, 512, 2>(hin, 92, ref_w1, ref_b1, r1, (bid >> 3) * 4, (bid & 7) * 64, smem, tid);
    grid_barrier(bars + 6);

    // final: refined -> cp out + q polyline. 128 rows.
    if (bid < 128)
        final_unit(bid, r1, ref_w2, ref_b2, out, qb, smem, tid);
    grid_barrier(bars + 7);

    // raster: 128 rows x 13 chunks of 64 pixels = 1664 units.
    for (int u = bid; u < 128 * 13; u += NBLK)
        raster_unit(u, qb, out, smem, tid);
}

extern "C" void kernel_launch(void* const* d_in, const int* in_sizes, int n_in,
                              void* d_out, int out_size, void* d_ws, size_t ws_size,
                              hipStream_t stream) {
    const float* x      = (const float*)d_in[0];
    const float* eps    = (const float*)d_in[1];
    const float* enc_w1 = (const float*)d_in[2];
    const float* enc_b1 = (const float*)d_in[3];
    const float* enc_w2 = (const float*)d_in[4];
    const float* enc_b2 = (const float*)d_in[5];
    const float* mu_w   = (const float*)d_in[6];
    const float* mu_b   = (const float*)d_in[7];
    const float* lv_w   = (const float*)d_in[8];
    const float* lv_b   = (const float*)d_in[9];
    const float* dec_w1 = (const float*)d_in[10];
    const float* dec_b1 = (const float*)d_in[11];
    const float* dec_w2 = (const float*)d_in[12];
    const float* dec_b2 = (const float*)d_in[13];
    const float* cp_w   = (const float*)d_in[14];
    const float* cp_b   = (const float*)d_in[15];
    const float* ref_w1 = (const float*)d_in[16];
    const float* ref_b1 = (const float*)d_in[17];
    const float* ref_w2 = (const float*)d_in[18];
    const float* ref_b2 = (const float*)d_in[19];
    const float* wd_w   = (const float*)d_in[20];
    const float* wd_b   = (const float*)d_in[21];
    const float* al_w   = (const float*)d_in[22];
    const float* al_b   = (const float*)d_in[23];

    float*    out  = (float*)d_out;
    unsigned* bars = (unsigned*)d_ws;          // 16 slots, zeroed below
    float*    wsf  = (float*)d_ws;

    float* h1  = wsf + 16;                     // 128*256
    float* h   = h1 + 32768;                   // 128*256
    float* hin = h + 32768;                    // 128*92 (z | pts_norm)
    float* d1  = hin + 11776;                  // 128*512
    float* h2  = d1 + 65536;                   // 128*512
    float* r1  = h2 + 65536;                   // 128*512
    float* qb  = r1 + 65536;                   // 128*128

    hipMemsetAsync(bars, 0, 64, stream);       // zero barrier slots (graph-safe)
    mega<<<NBLK, 256, 0, stream>>>(x, eps, enc_w1, enc_b1, enc_w2, enc_b2,
                                   mu_w, mu_b, lv_w, lv_b, dec_w1, dec_b1,
                                   dec_w2, dec_b2, cp_w, cp_b, ref_w1, ref_b1,
                                   ref_w2, ref_b2, wd_w, wd_b, al_w, al_b,
                                   out, bars, h1, h, hin, d1, h2, r1, qb);
}

// Round 3
// 314.344 us; speedup vs baseline: 1.6313x; 1.6313x over previous
//
#include <hip/hip_runtime.h>
#include <math.h>

// ---------------------------------------------------------------------------
// HierarchicalVAE, single persistent kernel for MI355X (gfx950), fp32.
// 256 blocks x 256 threads (co-resident), 5 device-scope grid barriers.
// Round-2 post-mortem: ACQUIRE-polling barriers cost ~50us each (L2
// invalidate storm). Fix: RELAXED polling + single acquire fence, and
// merge row-local stages to cut 8 barriers -> 5.
//
// Output layout (flat f32): rendered@0, mu@100352, logvar@108544,
// cp@116736, widths@124928, alphas@125184.
// ---------------------------------------------------------------------------

#define O_MU  100352
#define O_LV  108544
#define O_CP  116736
#define O_WD  124928
#define O_AL  125184

#define NBLK 256

// activation: 0=none 1=leaky_relu(0.2) 2=selu
template<int ACT>
__device__ __forceinline__ float act_fn(float x) {
    if (ACT == 1) return x >= 0.0f ? x : 0.2f * x;
    if (ACT == 2) {
        const float scale = 1.0507009873554805f;
        const float alpha = 1.6732632423543772f;
        return x > 0.0f ? scale * x : scale * (alpha * expm1f(x));
    }
    return x;
}

// Arrive: release RMW. Spin: RELAXED loads (no per-poll invalidates!).
// One agent acquire fence on exit for cross-XCD visibility.
__device__ __forceinline__ void grid_barrier(unsigned* bar) {
    __syncthreads();
    if (threadIdx.x == 0) {
        __hip_atomic_fetch_add(bar, 1u, __ATOMIC_RELEASE, __HIP_MEMORY_SCOPE_AGENT);
        while (__hip_atomic_load(bar, __ATOMIC_RELAXED, __HIP_MEMORY_SCOPE_AGENT) < (unsigned)NBLK)
            __builtin_amdgcn_s_sleep(8);
        __builtin_amdgcn_fence(__ATOMIC_ACQUIRE, "agent");
    }
    __syncthreads();
}

// one 4-rows x 64-cols tile of C[128,N] = act(A[128,lda] @ W[K,N] + b)
template<int K, int N, int ACT>
__device__ void gemm_unit(const float* __restrict__ A, int lda,
                          const float* __restrict__ W, const float* __restrict__ bias,
                          float* __restrict__ outp, int r0, int j0,
                          float* __restrict__ sA, int tid) {
    for (int idx = tid; idx < 4 * K; idx += 256) {
        int r = idx / K;
        int k = idx - r * K;
        sA[r * K + k] = A[(r0 + r) * lda + k];
    }
    __syncthreads();
    const int r = tid >> 6;
    const int j = j0 + (tid & 63);
    float acc0 = bias[j], acc1 = 0.f, acc2 = 0.f, acc3 = 0.f;
    const float* __restrict__ a = sA + r * K;
    for (int k = 0; k < K; k += 4) {
        acc0 = fmaf(a[k + 0], W[(k + 0) * N + j], acc0);
        acc1 = fmaf(a[k + 1], W[(k + 1) * N + j], acc1);
        acc2 = fmaf(a[k + 2], W[(k + 2) * N + j], acc2);
        acc3 = fmaf(a[k + 3], W[(k + 3) * N + j], acc3);
    }
    float acc = (acc0 + acc1) + (acc2 + acc3);
    outp[(r0 + r) * N + j] = act_fn<ACT>(acc);
}

// enc2 + mu + logvar + z for ONE row, entirely block-local.
__device__ void e2z_unit(int row, const float* __restrict__ h1,
                         const float* __restrict__ enc_w2, const float* __restrict__ enc_b2,
                         const float* __restrict__ mu_w, const float* __restrict__ mu_b,
                         const float* __restrict__ lv_w, const float* __restrict__ lv_b,
                         const float* __restrict__ eps,
                         float* __restrict__ out, float* __restrict__ zg,
                         float* __restrict__ smem, int tid) {
    float* sA = smem;        // 256: h1 row
    float* sH = smem + 256;  // 256: enc2 out
    float* sO = smem + 512;  // 128: mu|lv
    sA[tid] = h1[row * 256 + tid];
    __syncthreads();
    {   // enc2: col = tid
        float a0 = enc_b2[tid], a1 = 0.f, a2 = 0.f, a3 = 0.f;
        for (int k = 0; k < 256; k += 4) {
            a0 = fmaf(sA[k + 0], enc_w2[(k + 0) * 256 + tid], a0);
            a1 = fmaf(sA[k + 1], enc_w2[(k + 1) * 256 + tid], a1);
            a2 = fmaf(sA[k + 2], enc_w2[(k + 2) * 256 + tid], a2);
            a3 = fmaf(sA[k + 3], enc_w2[(k + 3) * 256 + tid], a3);
        }
        sH[tid] = act_fn<1>((a0 + a1) + (a2 + a3));
    }
    __syncthreads();
    {   // mu (o<64) / lv (o>=64): 128 outputs x 2 lanes
        const int o = tid >> 1, g = tid & 1;
        const int j = o & 63;
        const bool is_lv = o >= 64;
        const float* __restrict__ W = is_lv ? lv_w : mu_w;
        float acc = 0.f;
        for (int k = g; k < 256; k += 2) acc = fmaf(sH[k], W[k * 64 + j], acc);
        acc += __shfl_xor(acc, 1);
        if (g == 0) {
            acc += is_lv ? lv_b[j] : mu_b[j];
            out[(is_lv ? O_LV : O_MU) + row * 64 + j] = acc;
            sO[o] = acc;
        }
    }
    __syncthreads();
    if (tid < 64) {
        float mu = sO[tid], lv = sO[64 + tid];
        zg[row * 64 + tid] = fmaf(eps[row * 64 + tid], expf(0.5f * lv), mu);
    }
}

// heads + ref1 + ref2/final for ONE row, block-local (ref1 output stays in LDS)
__device__ void f_unit(int row, const float* __restrict__ h2g, const float* __restrict__ zg,
                       const float* __restrict__ cp_w, const float* __restrict__ cp_b,
                       const float* __restrict__ wd_w, const float* __restrict__ wd_b,
                       const float* __restrict__ al_w, const float* __restrict__ al_b,
                       const float* __restrict__ ref_w1, const float* __restrict__ ref_b1,
                       const float* __restrict__ ref_w2, const float* __restrict__ ref_b2,
                       float* __restrict__ out, float* __restrict__ qb,
                       float* __restrict__ smem, int tid) {
    float* sH2 = smem;         // 512: h2 row
    float* sIn = smem + 512;   // 92:  h_in row (z | pts_norm)
    float* sR  = smem + 608;   // 512: ref1 out
    float* sP  = smem + 1120;  // 52:  points
    sH2[tid] = h2g[row * 512 + tid];
    sH2[256 + tid] = h2g[row * 512 + 256 + tid];
    if (tid < 64) sIn[tid] = zg[row * 64 + tid];
    __syncthreads();
    {   // heads: 32 outputs x 8 lanes
        const int o = tid >> 3, g = tid & 7;
        const float* __restrict__ W;
        int ldw, col;
        if (o < 28)      { W = cp_w; ldw = 28; col = o; }
        else if (o < 30) { W = wd_w; ldw = 2;  col = o - 28; }
        else             { W = al_w; ldw = 2;  col = o - 30; }
        float acc = 0.f;
        for (int k = g; k < 512; k += 8) acc = fmaf(sH2[k], W[k * ldw + col], acc);
        acc += __shfl_xor(acc, 1);
        acc += __shfl_xor(acc, 2);
        acc += __shfl_xor(acc, 4);
        if (g == 0) {
            if (o < 28) {
                sIn[64 + o] = tanhf(acc + cp_b[col]);   // pts_norm
            } else if (o < 30) {
                float v = 1.f / (1.f + expf(-(acc + wd_b[col])));
                out[O_WD + row * 2 + col] = fmaf(v, 2.f, 1.f);
            } else {
                float v = 1.f / (1.f + expf(-(acc + al_b[col])));
                out[O_AL + row * 2 + col] = v;
            }
        }
    }
    __syncthreads();
    {   // ref1: 512 outputs, 2 per thread, K=92
        const float2* __restrict__ bv = (const float2*)ref_b1;
        float2 bb = bv[tid];
        float a0 = bb.x, a1 = bb.y;
        for (int k = 0; k < 92; k++) {
            float av = sIn[k];
            const float2* __restrict__ wv = (const float2*)(ref_w1 + k * 512);
            float2 ww = wv[tid];
            a0 = fmaf(av, ww.x, a0);
            a1 = fmaf(av, ww.y, a1);
        }
        sR[2 * tid]     = act_fn<2>(a0);
        sR[2 * tid + 1] = act_fn<2>(a1);
    }
    __syncthreads();
    {   // ref2: 52 outputs x 4 lanes -> points
        const int o = tid >> 2, g = tid & 3;
        float acc = 0.f;
        if (o < 52)
            for (int k = g; k < 512; k += 4) acc = fmaf(sR[k], ref_w2[k * 52 + o], acc);
        acc += __shfl_xor(acc, 1);
        acc += __shfl_xor(acc, 2);
        if (g == 0 && o < 52)
            sP[o] = fmaf(tanhf(acc + ref_b2[o]), 12.f, 14.f);  // *SCALE + HALF
    }
    __syncthreads();
    if (tid < 64) {   // control_points out
        int idx = tid;
        int p = idx >> 5, rest = idx & 31;
        int s = rest >> 3, kk = (rest >> 1) & 3, d = idx & 1;
        out[O_CP + row * 64 + idx] = sP[p * 26 + (3 * s + kk) * 2 + d];
    }
    if (tid < 128) {  // bezier sample points q
        int idx = tid;
        int p = idx >> 6, s = (idx >> 4) & 3, ti = (idx >> 1) & 7, d = idx & 1;
        float t = (float)ti / 7.0f;
        float mt = 1.0f - t;
        float c0 = mt * mt * mt;
        float c1 = 3.f * mt * mt * t;
        float c2 = 3.f * mt * t * t;
        float c3 = t * t * t;
        const float* base = sP + p * 26 + (3 * s) * 2 + d;
        qb[row * 128 + idx] = c0 * base[0] + c1 * base[2] + c2 * base[4] + c3 * base[6];
    }
}

// one (row, 64-pixel chunk) raster unit; thread = pixel*4 + AA subsample
__device__ void raster_unit(int u, const float* __restrict__ qb,
                            float* __restrict__ out, float* __restrict__ smem, int tid) {
    const int row = u / 13;
    const int chunk = u - row * 13;
    float* sWA = smem + 128;
    __syncthreads();  // protect LDS reuse across loop iterations
    if (tid < 128) smem[tid] = qb[row * 128 + tid];
    if (tid < 4) sWA[tid] = (tid < 2) ? out[O_WD + row * 2 + tid]
                                      : out[O_AL + row * 2 + (tid - 2)];
    __syncthreads();
    const int pixel = chunk * 64 + (tid >> 2);
    const int sub = tid & 3;
    if (pixel < 784) {
        const int py = pixel / 28;
        const int px = pixel - py * 28;
        const float sy = ((float)(2 * py + (sub >> 1)) + 0.5f) * 0.5f;
        const float sx = ((float)(2 * px + (sub & 1)) + 0.5f) * 0.5f;
        const float2* sQ = (const float2*)smem;
        float img = 1.0f;
#pragma unroll
        for (int p = 0; p < 2; p++) {
            float dmin2 = 1e30f;
            int cnt = 0;
            float2 cur = sQ[p * 32];
            bool bp = cur.y > sy;
#pragma unroll
            for (int m = 0; m < 32; m++) {
                float2 nxt = sQ[p * 32 + ((m + 1) & 31)];
                float dx = sx - cur.x;
                float dy = sy - cur.y;
                dmin2 = fminf(dmin2, fmaf(dx, dx, dy * dy));
                bool bn = nxt.y > sy;
                float den = nxt.y - cur.y + 1e-8f;
                float lhs = (sx - cur.x) * den;
                float rhs = (sy - cur.y) * (nxt.x - cur.x);
                if ((bp != bn) && ((lhs < rhs) == (den > 0.0f))) cnt++;
                cur = nxt;
                bp = bn;
            }
            float dist = sqrtf(dmin2);
            float stroke = fminf(fmaxf(fmaf(sWA[p], 0.5f, 0.5f) - dist, 0.f), 1.f);
            float cov = fmaxf((float)(cnt & 1), stroke);
            img *= fmaf(-sWA[2 + p], cov, 1.0f);
        }
        img += __shfl_xor(img, 1);
        img += __shfl_xor(img, 2);
        if (sub == 0) out[row * 784 + pixel] = 1.0f - 0.25f * img;
    }
}

__global__ __launch_bounds__(256, 1)
void mega(const float* __restrict__ x, const float* __restrict__ eps,
          const float* __restrict__ enc_w1, const float* __restrict__ enc_b1,
          const float* __restrict__ enc_w2, const float* __restrict__ enc_b2,
          const float* __restrict__ mu_w, const float* __restrict__ mu_b,
          const float* __restrict__ lv_w, const float* __restrict__ lv_b,
          const float* __restrict__ dec_w1, const float* __restrict__ dec_b1,
          const float* __restrict__ dec_w2, const float* __restrict__ dec_b2,
          const float* __restrict__ cp_w, const float* __restrict__ cp_b,
          const float* __restrict__ ref_w1, const float* __restrict__ ref_b1,
          const float* __restrict__ ref_w2, const float* __restrict__ ref_b2,
          const float* __restrict__ wd_w, const float* __restrict__ wd_b,
          const float* __restrict__ al_w, const float* __restrict__ al_b,
          float* __restrict__ out, unsigned* __restrict__ bars,
          float* __restrict__ h1, float* __restrict__ zg,
          float* __restrict__ d1, float* __restrict__ h2,
          float* __restrict__ qb) {
    __shared__ float smem[3136];
    const int bid = blockIdx.x;
    const int tid = threadIdx.x;

    // S1 enc1: 784->256 leaky, col-split. 128 units of 4 rows x 64 cols.
    if (bid < 128)
        gemm_unit<784, 256, 1>(x, 784, enc_w1, enc_b1, h1, (bid >> 2) * 4, (bid & 3) * 64, smem, tid);
    grid_barrier(bars + 0);

    // S2 enc2+mu+lv+z: row-local. 128 rows.
    if (bid < 128)
        e2z_unit(bid, h1, enc_w2, enc_b2, mu_w, mu_b, lv_w, lv_b, eps, out, zg, smem, tid);
    grid_barrier(bars + 1);

    // S3 dec1: 64->512 selu, col-split. 256 units.
    gemm_unit<64, 512, 2>(zg, 64, dec_w1, dec_b1, d1, (bid >> 3) * 4, (bid & 7) * 64, smem, tid);
    grid_barrier(bars + 2);

    // S4 dec2: 512->512 selu, col-split. 256 units.
    gemm_unit<512, 512, 2>(d1, 512, dec_w2, dec_b2, h2, (bid >> 3) * 4, (bid & 7) * 64, smem, tid);
    grid_barrier(bars + 3);

    // S5 heads+ref1+ref2+final: row-local. 128 rows.
    if (bid < 128)
        f_unit(bid, h2, zg, cp_w, cp_b, wd_w, wd_b, al_w, al_b,
               ref_w1, ref_b1, ref_w2, ref_b2, out, qb, smem, tid);
    grid_barrier(bars + 4);

    // S6 raster: 128 rows x 13 chunks of 64 pixels = 1664 units.
    for (int u = bid; u < 128 * 13; u += NBLK)
        raster_unit(u, qb, out, smem, tid);
}

extern "C" void kernel_launch(void* const* d_in, const int* in_sizes, int n_in,
                              void* d_out, int out_size, void* d_ws, size_t ws_size,
                              hipStream_t stream) {
    const float* x      = (const float*)d_in[0];
    const float* eps    = (const float*)d_in[1];
    const float* enc_w1 = (const float*)d_in[2];
    const float* enc_b1 = (const float*)d_in[3];
    const float* enc_w2 = (const float*)d_in[4];
    const float* enc_b2 = (const float*)d_in[5];
    const float* mu_w   = (const float*)d_in[6];
    const float* mu_b   = (const float*)d_in[7];
    const float* lv_w   = (const float*)d_in[8];
    const float* lv_b   = (const float*)d_in[9];
    const float* dec_w1 = (const float*)d_in[10];
    const float* dec_b1 = (const float*)d_in[11];
    const float* dec_w2 = (const float*)d_in[12];
    const float* dec_b2 = (const float*)d_in[13];
    const float* cp_w   = (const float*)d_in[14];
    const float* cp_b   = (const float*)d_in[15];
    const float* ref_w1 = (const float*)d_in[16];
    const float* ref_b1 = (const float*)d_in[17];
    const float* ref_w2 = (const float*)d_in[18];
    const float* ref_b2 = (const float*)d_in[19];
    const float* wd_w   = (const float*)d_in[20];
    const float* wd_b   = (const float*)d_in[21];
    const float* al_w   = (const float*)d_in[22];
    const float* al_b   = (const float*)d_in[23];

    float*    out  = (float*)d_out;
    unsigned* bars = (unsigned*)d_ws;   // 16 slots, zeroed below
    float*    wsf  = (float*)d_ws;

    float* h1 = wsf + 16;               // 128*256
    float* zg = h1 + 32768;             // 128*64
    float* d1 = zg + 8192;              // 128*512
    float* h2 = d1 + 65536;             // 128*512
    float* qb = h2 + 65536;             // 128*128

    hipMemsetAsync(bars, 0, 64, stream);
    mega<<<NBLK, 256, 0, stream>>>(x, eps, enc_w1, enc_b1, enc_w2, enc_b2,
                                   mu_w, mu_b, lv_w, lv_b, dec_w1, dec_b1,
                                   dec_w2, dec_b2, cp_w, cp_b, ref_w1, ref_b1,
                                   ref_w2, ref_b2, wd_w, wd_b, al_w, al_b,
                                   out, bars, h1, zg, d1, h2, qb);
}

// Round 4
// 232.903 us; speedup vs baseline: 2.2017x; 1.3497x over previous
//
#include <hip/hip_runtime.h>
#include <math.h>

// ---------------------------------------------------------------------------
// HierarchicalVAE, MI355X (gfx950), fp32. Round-4 structure: batch rows are
// fully independent -> ONE BLOCK PER ROW (128 blocks x 512 threads), entire
// network + raster per block, all intermediates in LDS. Zero grid barriers
// (Rounds 2/3 showed agent-scope barriers cost ~50us each on non-coherent
// per-XCD L2s). No workspace use at all.
//
// Output layout (flat f32): rendered@0, mu@100352, logvar@108544,
// cp@116736, widths@124928, alphas@125184.
// ---------------------------------------------------------------------------

#define O_MU  100352
#define O_LV  108544
#define O_CP  116736
#define O_WD  124928
#define O_AL  125184

__device__ __forceinline__ float leaky(float x) {
    return x >= 0.0f ? x : 0.2f * x;
}
__device__ __forceinline__ float selu(float x) {
    const float scale = 1.0507009873554805f;
    const float alpha = 1.6732632423543772f;
    return x > 0.0f ? scale * x : scale * (alpha * expm1f(x));
}

__global__ __launch_bounds__(512)
void pipeline(const float* __restrict__ x, const float* __restrict__ eps,
              const float* __restrict__ enc_w1, const float* __restrict__ enc_b1,
              const float* __restrict__ enc_w2, const float* __restrict__ enc_b2,
              const float* __restrict__ mu_w, const float* __restrict__ mu_b,
              const float* __restrict__ lv_w, const float* __restrict__ lv_b,
              const float* __restrict__ dec_w1, const float* __restrict__ dec_b1,
              const float* __restrict__ dec_w2, const float* __restrict__ dec_b2,
              const float* __restrict__ cp_w, const float* __restrict__ cp_b,
              const float* __restrict__ ref_w1, const float* __restrict__ ref_b1,
              const float* __restrict__ ref_w2, const float* __restrict__ ref_b2,
              const float* __restrict__ wd_w, const float* __restrict__ wd_b,
              const float* __restrict__ al_w, const float* __restrict__ al_b,
              float* __restrict__ out) {
    __shared__ float sX[784];    // input row
    __shared__ float sPart[512]; // split-K partials
    __shared__ float sH1[256];   // enc1 out
    __shared__ float sHe[256];   // enc2 out
    __shared__ float sML[128];   // mu | lv
    __shared__ float sIn[96];    // h_in: z(64) | pts_norm(28)
    __shared__ float sD1[512];   // dec1 out
    __shared__ float sH2[512];   // dec2 out
    __shared__ float sR1[512];   // ref1 out
    __shared__ float sP[56];     // points (52)
    __shared__ float sQ[128];    // polyline, [p*64 + m*2 + d]
    __shared__ float sWA[4];     // w0 w1 a0 a1

    const int row = blockIdx.x;
    const int tid = threadIdx.x;

    for (int i = tid; i < 784; i += 512) sX[i] = x[row * 784 + i];
    __syncthreads();

    // ---- enc1: 784 -> 256, leaky. 2-way split-K (g=tid>>8), col j=tid&255.
    {
        const int j = tid & 255, g = tid >> 8;
        const int k0 = g * 392;
        float a0 = 0.f, a1 = 0.f, a2 = 0.f, a3 = 0.f;
        for (int i = 0; i < 392; i += 4) {
            a0 = fmaf(sX[k0 + i + 0], enc_w1[(k0 + i + 0) * 256 + j], a0);
            a1 = fmaf(sX[k0 + i + 1], enc_w1[(k0 + i + 1) * 256 + j], a1);
            a2 = fmaf(sX[k0 + i + 2], enc_w1[(k0 + i + 2) * 256 + j], a2);
            a3 = fmaf(sX[k0 + i + 3], enc_w1[(k0 + i + 3) * 256 + j], a3);
        }
        sPart[tid] = (a0 + a1) + (a2 + a3);
    }
    __syncthreads();
    if (tid < 256) sH1[tid] = leaky(enc_b1[tid] + sPart[tid] + sPart[256 + tid]);
    __syncthreads();

    // ---- enc2: 256 -> 256, leaky. same split.
    {
        const int j = tid & 255, g = tid >> 8;
        const int k0 = g * 128;
        float a0 = 0.f, a1 = 0.f, a2 = 0.f, a3 = 0.f;
        for (int i = 0; i < 128; i += 4) {
            a0 = fmaf(sH1[k0 + i + 0], enc_w2[(k0 + i + 0) * 256 + j], a0);
            a1 = fmaf(sH1[k0 + i + 1], enc_w2[(k0 + i + 1) * 256 + j], a1);
            a2 = fmaf(sH1[k0 + i + 2], enc_w2[(k0 + i + 2) * 256 + j], a2);
            a3 = fmaf(sH1[k0 + i + 3], enc_w2[(k0 + i + 3) * 256 + j], a3);
        }
        sPart[tid] = (a0 + a1) + (a2 + a3);
    }
    __syncthreads();
    if (tid < 256) sHe[tid] = leaky(enc_b2[tid] + sPart[tid] + sPart[256 + tid]);
    __syncthreads();

    // ---- mu / logvar: 128 outputs x 4 lanes, K=256.
    {
        const int o = tid >> 2, g = tid & 3;
        const int j = o & 63;
        const bool is_lv = o >= 64;
        const float* __restrict__ W = is_lv ? lv_w : mu_w;
        float acc = 0.f;
        for (int k = g; k < 256; k += 4) acc = fmaf(sHe[k], W[k * 64 + j], acc);
        acc += __shfl_xor(acc, 1);
        acc += __shfl_xor(acc, 2);
        if (g == 0) {
            acc += is_lv ? lv_b[j] : mu_b[j];
            out[(is_lv ? O_LV : O_MU) + row * 64 + j] = acc;
            sML[o] = acc;
        }
    }
    __syncthreads();
    if (tid < 64)
        sIn[tid] = fmaf(eps[row * 64 + tid], expf(0.5f * sML[64 + tid]), sML[tid]);
    __syncthreads();

    // ---- dec1: 64 -> 512, selu. j = tid.
    {
        float acc = dec_b1[tid];
        for (int k = 0; k < 64; k++) acc = fmaf(sIn[k], dec_w1[k * 512 + tid], acc);
        sD1[tid] = selu(acc);
    }
    __syncthreads();

    // ---- dec2: 512 -> 512, selu. j = tid.
    {
        float a0 = dec_b2[tid], a1 = 0.f, a2 = 0.f, a3 = 0.f;
        for (int k = 0; k < 512; k += 4) {
            a0 = fmaf(sD1[k + 0], dec_w2[(k + 0) * 512 + tid], a0);
            a1 = fmaf(sD1[k + 1], dec_w2[(k + 1) * 512 + tid], a1);
            a2 = fmaf(sD1[k + 2], dec_w2[(k + 2) * 512 + tid], a2);
            a3 = fmaf(sD1[k + 3], dec_w2[(k + 3) * 512 + tid], a3);
        }
        sH2[tid] = selu((a0 + a1) + (a2 + a3));
    }
    __syncthreads();

    // ---- heads: 32 outputs x 16 lanes, K=512. cp->pts_norm, wd/al->out+LDS.
    {
        const int o = tid >> 4, g = tid & 15;
        const float* __restrict__ W;
        int ldw, col;
        if (o < 28)      { W = cp_w; ldw = 28; col = o; }
        else if (o < 30) { W = wd_w; ldw = 2;  col = o - 28; }
        else             { W = al_w; ldw = 2;  col = o - 30; }
        float acc = 0.f;
        for (int k = g; k < 512; k += 16) acc = fmaf(sH2[k], W[k * ldw + col], acc);
        acc += __shfl_xor(acc, 1);
        acc += __shfl_xor(acc, 2);
        acc += __shfl_xor(acc, 4);
        acc += __shfl_xor(acc, 8);
        if (g == 0) {
            if (o < 28) {
                sIn[64 + o] = tanhf(acc + cp_b[col]);          // pts_norm
            } else if (o < 30) {
                float v = 1.f / (1.f + expf(-(acc + wd_b[col])));
                v = fmaf(v, 2.f, 1.f);
                out[O_WD + row * 2 + col] = v;
                sWA[col] = v;
            } else {
                float v = 1.f / (1.f + expf(-(acc + al_b[col])));
                out[O_AL + row * 2 + col] = v;
                sWA[2 + col] = v;
            }
        }
    }
    __syncthreads();

    // ---- ref1: 92 -> 512, selu. j = tid.
    {
        float acc = ref_b1[tid];
        for (int k = 0; k < 92; k++) acc = fmaf(sIn[k], ref_w1[k * 512 + tid], acc);
        sR1[tid] = selu(acc);
    }
    __syncthreads();

    // ---- ref2: 52 outputs x 8 lanes, K=512 -> points.
    {
        const int o = tid >> 3, g = tid & 7;
        float acc = 0.f;
        if (o < 52)
            for (int k = g; k < 512; k += 8) acc = fmaf(sR1[k], ref_w2[k * 52 + o], acc);
        acc += __shfl_xor(acc, 1);
        acc += __shfl_xor(acc, 2);
        acc += __shfl_xor(acc, 4);
        if (g == 0 && o < 52)
            sP[o] = fmaf(tanhf(acc + ref_b2[o]), 12.f, 14.f);  // *SCALE + HALF
    }
    __syncthreads();

    // ---- control_points out + bezier polyline q
    if (tid < 64) {
        int idx = tid;
        int p = idx >> 5, rest = idx & 31;
        int s = rest >> 3, kk = (rest >> 1) & 3, d = idx & 1;
        out[O_CP + row * 64 + idx] = sP[p * 26 + (3 * s + kk) * 2 + d];
    }
    if (tid < 128) {
        int idx = tid;
        int p = idx >> 6, s = (idx >> 4) & 3, ti = (idx >> 1) & 7, d = idx & 1;
        float t = (float)ti / 7.0f;
        float mt = 1.0f - t;
        float c0 = mt * mt * mt;
        float c1 = 3.f * mt * mt * t;
        float c2 = 3.f * mt * t * t;
        float c3 = t * t * t;
        const float* base = sP + p * 26 + (3 * s) * 2 + d;
        sQ[idx] = c0 * base[0] + c1 * base[2] + c2 * base[4] + c3 * base[6];
    }
    __syncthreads();

    // ---- raster: 784 px x 4 AA subsamples = 3136 units, grid-stride.
    const float2* __restrict__ sQ2 = (const float2*)sQ;
    for (int u = tid; u < 3136; u += 512) {
        const int pixel = u >> 2;
        const int sub = u & 3;
        const int py = pixel / 28;
        const int px = pixel - py * 28;
        const float sy = ((float)(2 * py + (sub >> 1)) + 0.5f) * 0.5f;
        const float sx = ((float)(2 * px + (sub & 1)) + 0.5f) * 0.5f;
        float img = 1.0f;
#pragma unroll
        for (int p = 0; p < 2; p++) {
            float dmin2 = 1e30f;
            int cnt = 0;
            float2 cur = sQ2[p * 32];
            bool bp = cur.y > sy;
#pragma unroll
            for (int m = 0; m < 32; m++) {
                float2 nxt = sQ2[p * 32 + ((m + 1) & 31)];
                float dx = sx - cur.x;
                float dy = sy - cur.y;
                dmin2 = fminf(dmin2, fmaf(dx, dx, dy * dy));
                bool bn = nxt.y > sy;
                float den = nxt.y - cur.y + 1e-8f;
                float lhs = dx * den;
                float rhs = dy * (nxt.x - cur.x);
                if ((bp != bn) && ((lhs < rhs) == (den > 0.0f))) cnt++;
                cur = nxt;
                bp = bn;
            }
            float dist = sqrtf(dmin2);
            float stroke = fminf(fmaxf(fmaf(sWA[p], 0.5f, 0.5f) - dist, 0.f), 1.f);
            float cov = fmaxf((float)(cnt & 1), stroke);
            img *= fmaf(-sWA[2 + p], cov, 1.0f);
        }
        img += __shfl_xor(img, 1);
        img += __shfl_xor(img, 2);
        if (sub == 0) out[row * 784 + pixel] = 1.0f - 0.25f * img;
    }
}

extern "C" void kernel_launch(void* const* d_in, const int* in_sizes, int n_in,
                              void* d_out, int out_size, void* d_ws, size_t ws_size,
                              hipStream_t stream) {
    const float* x      = (const float*)d_in[0];
    const float* eps    = (const float*)d_in[1];
    const float* enc_w1 = (const float*)d_in[2];
    const float* enc_b1 = (const float*)d_in[3];
    const float* enc_w2 = (const float*)d_in[4];
    const float* enc_b2 = (const float*)d_in[5];
    const float* mu_w   = (const float*)d_in[6];
    const float* mu_b   = (const float*)d_in[7];
    const float* lv_w   = (const float*)d_in[8];
    const float* lv_b   = (const float*)d_in[9];
    const float* dec_w1 = (const float*)d_in[10];
    const float* dec_b1 = (const float*)d_in[11];
    const float* dec_w2 = (const float*)d_in[12];
    const float* dec_b2 = (const float*)d_in[13];
    const float* cp_w   = (const float*)d_in[14];
    const float* cp_b   = (const float*)d_in[15];
    const float* ref_w1 = (const float*)d_in[16];
    const float* ref_b1 = (const float*)d_in[17];
    const float* ref_w2 = (const float*)d_in[18];
    const float* ref_b2 = (const float*)d_in[19];
    const float* wd_w   = (const float*)d_in[20];
    const float* wd_b   = (const float*)d_in[21];
    const float* al_w   = (const float*)d_in[22];
    const float* al_b   = (const float*)d_in[23];

    float* out = (float*)d_out;

    pipeline<<<128, 512, 0, stream>>>(x, eps, enc_w1, enc_b1, enc_w2, enc_b2,
                                      mu_w, mu_b, lv_w, lv_b, dec_w1, dec_b1,
                                      dec_w2, dec_b2, cp_w, cp_b, ref_w1, ref_b1,
                                      ref_w2, ref_b2, wd_w, wd_b, al_w, al_b,
                                      out);
}